// Round 1
// baseline (992.868 us; speedup 1.0000x reference)
//
#include <hip/hip_runtime.h>
#include <hip/hip_bf16.h>
#include <cstdint>
#include <cstddef>

#define D_MODEL 1024
#define NH      16
#define DH      64
#define LSEQ    2048
#define BATCH   4
#define NTOK    8192      // BATCH * LSEQ
#define K3      3072

typedef __attribute__((ext_vector_type(8))) short  short8;
typedef __attribute__((ext_vector_type(4))) float  floatx4;

__device__ __forceinline__ unsigned short f2bf_bits(float f) {
  __hip_bfloat16 h = __float2bfloat16(f);
  return __builtin_bit_cast(unsigned short, h);
}

__device__ __forceinline__ void gld_lds16(const void* g, void* l) {
  __builtin_amdgcn_global_load_lds(
      (const __attribute__((address_space(1))) void*)g,
      (__attribute__((address_space(3))) void*)l,
      16, 0, 0);
}

// ---------------------------------------------------------------- transpose+cast
// src: fp32 [R][C] -> dst: bf16 [C][R]
__global__ __launch_bounds__(256)
void transpose_cast(const float* __restrict__ src, __hip_bfloat16* __restrict__ dst,
                    int R, int C) {
  __shared__ float tile[32][33];
  const int c0 = blockIdx.x * 32, r0 = blockIdx.y * 32;
  const int x = threadIdx.x, y = threadIdx.y;   // 32 x 8
  #pragma unroll
  for (int j = 0; j < 32; j += 8)
    tile[y + j][x] = src[(size_t)(r0 + y + j) * C + c0 + x];
  __syncthreads();
  #pragma unroll
  for (int j = 0; j < 32; j += 8)
    dst[(size_t)(c0 + y + j) * R + r0 + x] = __float2bfloat16(tile[x][y + j]);
}

// ---------------------------------------------------------------- LayerNorm(x) -> bf16
__global__ __launch_bounds__(256)
void ln_kernel(const float* __restrict__ x, const float* __restrict__ w,
               const float* __restrict__ bb, __hip_bfloat16* __restrict__ h) {
  const int t = blockIdx.x, tid = threadIdx.x;
  const float4 v = reinterpret_cast<const float4*>(x + (size_t)t * D_MODEL)[tid];
  float s  = v.x + v.y + v.z + v.w;
  float ss = v.x*v.x + v.y*v.y + v.z*v.z + v.w*v.w;
  #pragma unroll
  for (int off = 32; off > 0; off >>= 1) {
    s  += __shfl_down(s, off);
    ss += __shfl_down(ss, off);
  }
  __shared__ float red[8];
  if ((tid & 63) == 0) { red[(tid >> 6) * 2] = s; red[(tid >> 6) * 2 + 1] = ss; }
  __syncthreads();
  s  = red[0] + red[2] + red[4] + red[6];
  ss = red[1] + red[3] + red[5] + red[7];
  const float mu  = s * (1.f / D_MODEL);
  const float var = ss * (1.f / D_MODEL) - mu * mu;
  const float rs  = rsqrtf(var + 1e-5f);
  const float4 wv = reinterpret_cast<const float4*>(w)[tid];
  const float4 bv = reinterpret_cast<const float4*>(bb)[tid];
  ushort4 o;
  o.x = f2bf_bits((v.x - mu) * rs * wv.x + bv.x);
  o.y = f2bf_bits((v.y - mu) * rs * wv.y + bv.y);
  o.z = f2bf_bits((v.z - mu) * rs * wv.z + bv.z);
  o.w = f2bf_bits((v.w - mu) * rs * wv.w + bv.w);
  reinterpret_cast<ushort4*>(h + (size_t)t * D_MODEL)[tid] = o;
}

// ---------------------------------------------------------------- bf16 GEMM, Bt layout
// A: bf16 [M][K] row-major, Bt: bf16 [N][K] (B transposed), C: fp32 [M][N]
__global__ __launch_bounds__(256, 2)
void gemm_bt(const __hip_bfloat16* __restrict__ A, const __hip_bfloat16* __restrict__ Bt,
             float* __restrict__ C, int M, int N, int K) {
  const int tid  = threadIdx.x;
  const int lane = tid & 63;
  const int wave = tid >> 6;
  const int bm = blockIdx.y * 128;
  const int bn = blockIdx.x * 128;
  const int wm = (wave & 1) * 64;
  const int wn = (wave >> 1) * 64;
  const int quad = lane >> 4;
  const int l16  = lane & 15;

  __shared__ __align__(16) __hip_bfloat16 As[128 * 32];
  __shared__ __align__(16) __hip_bfloat16 Bs[128 * 32];

  floatx4 acc[4][4];
  #pragma unroll
  for (int i = 0; i < 4; i++)
    #pragma unroll
    for (int j = 0; j < 4; j++) {
      floatx4 z = {0.f, 0.f, 0.f, 0.f};
      acc[i][j] = z;
    }

  const __hip_bfloat16* Ab = A  + (size_t)bm * K;
  const __hip_bfloat16* Bb = Bt + (size_t)bn * K;
  const int rowa = tid >> 2;
  const int kc   = (tid & 3) * 8;

  for (int k0 = 0; k0 < K; k0 += 32) {
    __syncthreads();
    gld_lds16(Ab + (size_t)rowa        * K + (k0 + kc), (char*)As + tid * 16);
    gld_lds16(Ab + (size_t)(rowa + 64) * K + (k0 + kc), (char*)As + 4096 + tid * 16);
    gld_lds16(Bb + (size_t)rowa        * K + (k0 + kc), (char*)Bs + tid * 16);
    gld_lds16(Bb + (size_t)(rowa + 64) * K + (k0 + kc), (char*)Bs + 4096 + tid * 16);
    __syncthreads();
    short8 af[4], bfr[4];
    #pragma unroll
    for (int i = 0; i < 4; i++)
      af[i] = *reinterpret_cast<const short8*>(As + (wm + i * 16 + l16) * 32 + quad * 8);
    #pragma unroll
    for (int j = 0; j < 4; j++)
      bfr[j] = *reinterpret_cast<const short8*>(Bs + (wn + j * 16 + l16) * 32 + quad * 8);
    #pragma unroll
    for (int i = 0; i < 4; i++)
      #pragma unroll
      for (int j = 0; j < 4; j++)
        acc[i][j] = __builtin_amdgcn_mfma_f32_16x16x32_bf16(af[i], bfr[j], acc[i][j], 0, 0, 0);
  }

  #pragma unroll
  for (int i = 0; i < 4; i++)
    #pragma unroll
    for (int j = 0; j < 4; j++) {
      const int row0 = bm + wm + i * 16 + quad * 4;
      const int col  = bn + wn + j * 16 + l16;
      #pragma unroll
      for (int r = 0; r < 4; r++)
        C[(size_t)(row0 + r) * N + col] = acc[i][j][r];
    }
}

// ---------------------------------------------------------------- segment bounds
__global__ __launch_bounds__(256)
void seg_kernel(const int* __restrict__ sid, int* __restrict__ segstart,
                int* __restrict__ segend) {
  const int i = blockIdx.x * 256 + threadIdx.x;   // 0..8191
  const int b = i >> 11, l = i & 2047;
  const int* row = sid + (size_t)b * LSEQ;
  const int v = row[l];
  int lo = 0, hi = l;
  while (lo < hi) { int mid = (lo + hi) >> 1; if (row[mid] < v) lo = mid + 1; else hi = mid; }
  segstart[i] = lo;
  lo = l + 1; hi = LSEQ;
  while (lo < hi) { int mid = (lo + hi) >> 1; if (row[mid] <= v) lo = mid + 1; else hi = mid; }
  segend[i] = lo;
}

// ---------------------------------------------------------------- QK-LN + RoPE + scatter
// qkv: fp32 [NTOK][3072]; outputs fp32 [B][H][L][DH]
__global__ __launch_bounds__(256)
void rope_kernel(const float* __restrict__ qkv, const float* __restrict__ qw,
                 const float* __restrict__ kw, float* __restrict__ qT,
                 float* __restrict__ kT, float* __restrict__ vT) {
  const int t = blockIdx.x, tid = threadIdx.x;
  const int b = t >> 11, l = t & 2047;
  const float* row = qkv + (size_t)t * K3;
  const float4 q4 = reinterpret_cast<const float4*>(row)[tid];
  const float4 k4 = reinterpret_cast<const float4*>(row + 1024)[tid];
  const float4 v4 = reinterpret_cast<const float4*>(row + 2048)[tid];
  float qs  = q4.x + q4.y + q4.z + q4.w;
  float qss = q4.x*q4.x + q4.y*q4.y + q4.z*q4.z + q4.w*q4.w;
  float ks  = k4.x + k4.y + k4.z + k4.w;
  float kss = k4.x*k4.x + k4.y*k4.y + k4.z*k4.z + k4.w*k4.w;
  #pragma unroll
  for (int off = 32; off > 0; off >>= 1) {
    qs  += __shfl_down(qs, off);  qss += __shfl_down(qss, off);
    ks  += __shfl_down(ks, off);  kss += __shfl_down(kss, off);
  }
  __shared__ float red[16];
  const int w = tid >> 6;
  if ((tid & 63) == 0) {
    red[w*4] = qs; red[w*4+1] = qss; red[w*4+2] = ks; red[w*4+3] = kss;
  }
  __syncthreads();
  qs  = red[0] + red[4] + red[8]  + red[12];
  qss = red[1] + red[5] + red[9]  + red[13];
  ks  = red[2] + red[6] + red[10] + red[14];
  kss = red[3] + red[7] + red[11] + red[15];
  const float qmu = qs * (1.f/1024), qvar = qss * (1.f/1024) - qmu*qmu;
  const float qrs = rsqrtf(qvar + 1e-5f);
  const float kmu = ks * (1.f/1024), kvar = kss * (1.f/1024) - kmu*kmu;
  const float krs = rsqrtf(kvar + 1e-5f);

  __shared__ float qn[1024];
  __shared__ float kn[1024];
  const float4 qwv = reinterpret_cast<const float4*>(qw)[tid];
  const float4 kwv = reinterpret_cast<const float4*>(kw)[tid];
  const int d = tid * 4;
  qn[d+0] = (q4.x - qmu) * qrs * qwv.x;
  qn[d+1] = (q4.y - qmu) * qrs * qwv.y;
  qn[d+2] = (q4.z - qmu) * qrs * qwv.z;
  qn[d+3] = (q4.w - qmu) * qrs * qwv.w;
  kn[d+0] = (k4.x - kmu) * krs * kwv.x;
  kn[d+1] = (k4.y - kmu) * krs * kwv.y;
  kn[d+2] = (k4.z - kmu) * krs * kwv.z;
  kn[d+3] = (k4.w - kmu) * krs * kwv.w;
  __syncthreads();

  const int hh = d >> 6, dh = d & 63;
  float oq[4], ok[4];
  #pragma unroll
  for (int i = 0; i < 4; i++) {
    const int dd = dh + i;
    const int j = dd & 31;
    const float th = (float)l * __expf(-(float)j * 0.28782313662425575f); // ln(1e4)/32
    const float cs = cosf(th), sn = sinf(th);
    const float qp = (dd < 32) ? -qn[d + i + 32] : qn[d + i - 32];
    const float kp = (dd < 32) ? -kn[d + i + 32] : kn[d + i - 32];
    oq[i] = qn[d + i] * cs + qp * sn;
    ok[i] = kn[d + i] * cs + kp * sn;
  }
  const size_t ob = ((size_t)(b * NH + hh) * LSEQ + l) * DH + dh;
  *reinterpret_cast<float4*>(qT + ob) = make_float4(oq[0], oq[1], oq[2], oq[3]);
  *reinterpret_cast<float4*>(kT + ob) = make_float4(ok[0], ok[1], ok[2], ok[3]);
  *reinterpret_cast<float4*>(vT + ob) = v4;
}

// ---------------------------------------------------------------- segment-aware attention
// one wave per 64 queries of one (b,h); fp32 online softmax; ctx: bf16 [B][L][H][DH]
__global__ __launch_bounds__(64)
void attn_kernel(const float* __restrict__ qT, const float* __restrict__ kT,
                 const float* __restrict__ vT, const int* __restrict__ segs,
                 const int* __restrict__ sege, __hip_bfloat16* __restrict__ ctx) {
  const int lane = threadIdx.x;
  const int qt = blockIdx.x, h = blockIdx.y, b = blockIdx.z;
  const int qpos = qt * 64 + lane;
  const size_t bh = (size_t)(b * NH + h) * LSEQ;
  const float* qrow = qT + (bh + qpos) * DH;
  float4 qv[16];
  #pragma unroll
  for (int c = 0; c < 16; c++) qv[c] = reinterpret_cast<const float4*>(qrow)[c];
  const int start = segs[b * LSEQ + qpos];
  const int end   = sege[b * LSEQ + qpos];
  const int kmin  = __shfl(start, 0) & ~63;
  const int kmax  = __shfl(end, 63);

  __shared__ __align__(16) float Ks[64 * 68];
  __shared__ __align__(16) float Vs[64 * 68];

  float4 acc4[16];
  #pragma unroll
  for (int c = 0; c < 16; c++) acc4[c] = make_float4(0.f, 0.f, 0.f, 0.f);
  float m = -1e30f, lsum = 0.f;

  const float* Kb = kT + bh * DH;
  const float* Vb = vT + bh * DH;

  for (int kk = kmin; kk < kmax; kk += 64) {
    __syncthreads();
    #pragma unroll
    for (int rep = 0; rep < 16; rep++) {
      const int idx = rep * 64 + lane;
      const int r = idx >> 4, c = idx & 15;
      int kr = kk + r; if (kr > LSEQ - 1) kr = LSEQ - 1;
      reinterpret_cast<float4*>(Ks + r * 68)[c] =
          reinterpret_cast<const float4*>(Kb + (size_t)kr * DH)[c];
      reinterpret_cast<float4*>(Vs + r * 68)[c] =
          reinterpret_cast<const float4*>(Vb + (size_t)kr * DH)[c];
    }
    __syncthreads();

    for (int kq = 0; kq < 64; kq += 4) {
      float s0 = 0.f, s1 = 0.f, s2 = 0.f, s3 = 0.f;
      #pragma unroll
      for (int c = 0; c < 16; c++) {
        const float4 a  = reinterpret_cast<const float4*>(Ks + (kq + 0) * 68)[c];
        const float4 bb = reinterpret_cast<const float4*>(Ks + (kq + 1) * 68)[c];
        const float4 cc = reinterpret_cast<const float4*>(Ks + (kq + 2) * 68)[c];
        const float4 dd = reinterpret_cast<const float4*>(Ks + (kq + 3) * 68)[c];
        s0 = fmaf(a.x,  qv[c].x, s0); s0 = fmaf(a.y,  qv[c].y, s0);
        s0 = fmaf(a.z,  qv[c].z, s0); s0 = fmaf(a.w,  qv[c].w, s0);
        s1 = fmaf(bb.x, qv[c].x, s1); s1 = fmaf(bb.y, qv[c].y, s1);
        s1 = fmaf(bb.z, qv[c].z, s1); s1 = fmaf(bb.w, qv[c].w, s1);
        s2 = fmaf(cc.x, qv[c].x, s2); s2 = fmaf(cc.y, qv[c].y, s2);
        s2 = fmaf(cc.z, qv[c].z, s2); s2 = fmaf(cc.w, qv[c].w, s2);
        s3 = fmaf(dd.x, qv[c].x, s3); s3 = fmaf(dd.y, qv[c].y, s3);
        s3 = fmaf(dd.z, qv[c].z, s3); s3 = fmaf(dd.w, qv[c].w, s3);
      }
      const int kb_ = kk + kq;
      const bool v0 = (kb_ + 0 >= start) && (kb_ + 0 < end);
      const bool v1 = (kb_ + 1 >= start) && (kb_ + 1 < end);
      const bool v2 = (kb_ + 2 >= start) && (kb_ + 2 < end);
      const bool v3 = (kb_ + 3 >= start) && (kb_ + 3 < end);
      s0 = v0 ? s0 * 0.125f : -1e30f;
      s1 = v1 ? s1 * 0.125f : -1e30f;
      s2 = v2 ? s2 * 0.125f : -1e30f;
      s3 = v3 ? s3 * 0.125f : -1e30f;
      const float mnew = fmaxf(fmaxf(fmaxf(s0, s1), fmaxf(s2, s3)), m);
      const float alpha = __expf(m - mnew);
      const float p0 = v0 ? __expf(s0 - mnew) : 0.f;
      const float p1 = v1 ? __expf(s1 - mnew) : 0.f;
      const float p2 = v2 ? __expf(s2 - mnew) : 0.f;
      const float p3 = v3 ? __expf(s3 - mnew) : 0.f;
      lsum = fmaf(lsum, alpha, (p0 + p1) + (p2 + p3));
      m = mnew;
      #pragma unroll
      for (int c = 0; c < 16; c++) {
        const float4 va = reinterpret_cast<const float4*>(Vs + (kq + 0) * 68)[c];
        const float4 vb = reinterpret_cast<const float4*>(Vs + (kq + 1) * 68)[c];
        const float4 vc = reinterpret_cast<const float4*>(Vs + (kq + 2) * 68)[c];
        const float4 vd = reinterpret_cast<const float4*>(Vs + (kq + 3) * 68)[c];
        float tx = p0 * va.x; tx = fmaf(p1, vb.x, tx); tx = fmaf(p2, vc.x, tx); tx = fmaf(p3, vd.x, tx);
        float ty = p0 * va.y; ty = fmaf(p1, vb.y, ty); ty = fmaf(p2, vc.y, ty); ty = fmaf(p3, vd.y, ty);
        float tz = p0 * va.z; tz = fmaf(p1, vb.z, tz); tz = fmaf(p2, vc.z, tz); tz = fmaf(p3, vd.z, tz);
        float tw = p0 * va.w; tw = fmaf(p1, vb.w, tw); tw = fmaf(p2, vc.w, tw); tw = fmaf(p3, vd.w, tw);
        acc4[c].x = fmaf(acc4[c].x, alpha, tx);
        acc4[c].y = fmaf(acc4[c].y, alpha, ty);
        acc4[c].z = fmaf(acc4[c].z, alpha, tz);
        acc4[c].w = fmaf(acc4[c].w, alpha, tw);
      }
    }
  }

  const float inv = 1.0f / lsum;
  __hip_bfloat16* ob = ctx + ((size_t)(b * LSEQ + qpos) * D_MODEL) + h * DH;
  #pragma unroll
  for (int c = 0; c < 16; c++) {
    ushort4 o;
    o.x = f2bf_bits(acc4[c].x * inv);
    o.y = f2bf_bits(acc4[c].y * inv);
    o.z = f2bf_bits(acc4[c].z * inv);
    o.w = f2bf_bits(acc4[c].w * inv);
    reinterpret_cast<ushort4*>(ob)[c] = o;
  }
}

// ---------------------------------------------------------------- launch
extern "C" void kernel_launch(void* const* d_in, const int* in_sizes, int n_in,
                              void* d_out, int out_size, void* d_ws, size_t ws_size,
                              hipStream_t stream) {
  const float* x      = (const float*)d_in[0];
  const int*   sid    = (const int*)d_in[1];
  const float* ln_w   = (const float*)d_in[2];
  const float* ln_b   = (const float*)d_in[3];
  const float* w_qkv  = (const float*)d_in[4];
  const float* q_ln_w = (const float*)d_in[5];
  const float* k_ln_w = (const float*)d_in[6];
  const float* w_out  = (const float*)d_in[7];
  float* out = (float*)d_out;
  char* ws = (char*)d_ws;

  constexpr size_t OFF_WQKVT = 0;                       // 3072*1024*2  = 6291456
  constexpr size_t OFF_WOUTT = 6291456;                 // 1024*1024*2  = 2097152
  constexpr size_t OFF_H     = 8388608;                 // 8192*1024*2  = 16777216
  constexpr size_t OFF_QKV   = 25165824;                // 8192*3072*4  = 100663296
  constexpr size_t OFF_QT    = 125829120;               // 33554432
  constexpr size_t OFF_KT    = 159383552;               // 33554432
  constexpr size_t OFF_VT    = 192937984;               // 33554432
  constexpr size_t OFF_CTX   = 226492416;               // 16777216
  constexpr size_t OFF_SEGS  = 243269632;               // 32768
  constexpr size_t OFF_SEGE  = 243302400;               // 32768

  __hip_bfloat16* wqkvT = (__hip_bfloat16*)(ws + OFF_WQKVT);
  __hip_bfloat16* woutT = (__hip_bfloat16*)(ws + OFF_WOUTT);
  __hip_bfloat16* hbuf  = (__hip_bfloat16*)(ws + OFF_H);
  float*          qkv   = (float*)(ws + OFF_QKV);
  float*          qT    = (float*)(ws + OFF_QT);
  float*          kT    = (float*)(ws + OFF_KT);
  float*          vT    = (float*)(ws + OFF_VT);
  __hip_bfloat16* ctx   = (__hip_bfloat16*)(ws + OFF_CTX);
  int*            segst = (int*)(ws + OFF_SEGS);
  int*            segen = (int*)(ws + OFF_SEGE);

  transpose_cast<<<dim3(96, 32), dim3(32, 8), 0, stream>>>(w_qkv, wqkvT, 1024, 3072);
  transpose_cast<<<dim3(32, 32), dim3(32, 8), 0, stream>>>(w_out, woutT, 1024, 1024);
  ln_kernel<<<NTOK, 256, 0, stream>>>(x, ln_w, ln_b, hbuf);
  gemm_bt<<<dim3(K3 / 128, NTOK / 128), 256, 0, stream>>>(hbuf, wqkvT, qkv, NTOK, K3, 1024);
  seg_kernel<<<NTOK / 256, 256, 0, stream>>>(sid, segst, segen);
  rope_kernel<<<NTOK, 256, 0, stream>>>(qkv, q_ln_w, k_ln_w, qT, kT, vT);
  attn_kernel<<<dim3(LSEQ / 64, NH, BATCH), 64, 0, stream>>>(qT, kT, vT, segst, segen, ctx);
  gemm_bt<<<dim3(D_MODEL / 128, NTOK / 128), 256, 0, stream>>>(ctx, woutT, out, NTOK, D_MODEL, 1024);
}

// Round 2
// 321.312 us; speedup vs baseline: 3.0900x; 3.0900x over previous
//
#include <hip/hip_runtime.h>
#include <hip/hip_bf16.h>
#include <cstdint>
#include <cstddef>

#define D_MODEL 1024
#define NH      16
#define DH      64
#define LSEQ    2048
#define BATCH   4
#define NTOK    8192      // BATCH * LSEQ
#define K3      3072

typedef __attribute__((ext_vector_type(8))) short  short8;
typedef __attribute__((ext_vector_type(4))) float  floatx4;

__device__ __forceinline__ unsigned short f2bf_bits(float f) {
  __hip_bfloat16 h = __float2bfloat16(f);
  return __builtin_bit_cast(unsigned short, h);
}

__device__ __forceinline__ void gld_lds16(const void* g, void* l) {
  __builtin_amdgcn_global_load_lds(
      (const __attribute__((address_space(1))) void*)g,
      (__attribute__((address_space(3))) void*)l,
      16, 0, 0);
}

// ---------------------------------------------------------------- transpose+cast
// src: fp32 [R][C] -> dst: bf16 [C][R]
__global__ __launch_bounds__(256)
void transpose_cast(const float* __restrict__ src, __hip_bfloat16* __restrict__ dst,
                    int R, int C) {
  __shared__ float tile[32][33];
  const int c0 = blockIdx.x * 32, r0 = blockIdx.y * 32;
  const int x = threadIdx.x, y = threadIdx.y;   // 32 x 8
  #pragma unroll
  for (int j = 0; j < 32; j += 8)
    tile[y + j][x] = src[(size_t)(r0 + y + j) * C + c0 + x];
  __syncthreads();
  #pragma unroll
  for (int j = 0; j < 32; j += 8)
    dst[(size_t)(c0 + y + j) * R + r0 + x] = __float2bfloat16(tile[x][y + j]);
}

// ---------------------------------------------------------------- LayerNorm(x) -> bf16
__global__ __launch_bounds__(256)
void ln_kernel(const float* __restrict__ x, const float* __restrict__ w,
               const float* __restrict__ bb, __hip_bfloat16* __restrict__ h) {
  const int t = blockIdx.x, tid = threadIdx.x;
  const float4 v = reinterpret_cast<const float4*>(x + (size_t)t * D_MODEL)[tid];
  float s  = v.x + v.y + v.z + v.w;
  float ss = v.x*v.x + v.y*v.y + v.z*v.z + v.w*v.w;
  #pragma unroll
  for (int off = 32; off > 0; off >>= 1) {
    s  += __shfl_down(s, off);
    ss += __shfl_down(ss, off);
  }
  __shared__ float red[8];
  if ((tid & 63) == 0) { red[(tid >> 6) * 2] = s; red[(tid >> 6) * 2 + 1] = ss; }
  __syncthreads();
  s  = red[0] + red[2] + red[4] + red[6];
  ss = red[1] + red[3] + red[5] + red[7];
  const float mu  = s * (1.f / D_MODEL);
  const float var = ss * (1.f / D_MODEL) - mu * mu;
  const float rs  = rsqrtf(var + 1e-5f);
  const float4 wv = reinterpret_cast<const float4*>(w)[tid];
  const float4 bv = reinterpret_cast<const float4*>(bb)[tid];
  ushort4 o;
  o.x = f2bf_bits((v.x - mu) * rs * wv.x + bv.x);
  o.y = f2bf_bits((v.y - mu) * rs * wv.y + bv.y);
  o.z = f2bf_bits((v.z - mu) * rs * wv.z + bv.z);
  o.w = f2bf_bits((v.w - mu) * rs * wv.w + bv.w);
  reinterpret_cast<ushort4*>(h + (size_t)t * D_MODEL)[tid] = o;
}

// ---------------------------------------------------------------- bf16 GEMM, Bt layout
// A: bf16 [M][K] row-major, Bt: bf16 [N][K] (B transposed), C: fp32 [M][N]
__global__ __launch_bounds__(256, 2)
void gemm_bt(const __hip_bfloat16* __restrict__ A, const __hip_bfloat16* __restrict__ Bt,
             float* __restrict__ C, int M, int N, int K) {
  const int tid  = threadIdx.x;
  const int lane = tid & 63;
  const int wave = tid >> 6;
  const int bm = blockIdx.y * 128;
  const int bn = blockIdx.x * 128;
  const int wm = (wave & 1) * 64;
  const int wn = (wave >> 1) * 64;
  const int quad = lane >> 4;
  const int l16  = lane & 15;

  __shared__ __align__(16) __hip_bfloat16 As[128 * 32];
  __shared__ __align__(16) __hip_bfloat16 Bs[128 * 32];

  floatx4 acc[4][4];
  #pragma unroll
  for (int i = 0; i < 4; i++)
    #pragma unroll
    for (int j = 0; j < 4; j++) {
      floatx4 z = {0.f, 0.f, 0.f, 0.f};
      acc[i][j] = z;
    }

  const __hip_bfloat16* Ab = A  + (size_t)bm * K;
  const __hip_bfloat16* Bb = Bt + (size_t)bn * K;
  const int rowa = tid >> 2;
  const int kc   = (tid & 3) * 8;

  for (int k0 = 0; k0 < K; k0 += 32) {
    __syncthreads();
    gld_lds16(Ab + (size_t)rowa        * K + (k0 + kc), (char*)As + tid * 16);
    gld_lds16(Ab + (size_t)(rowa + 64) * K + (k0 + kc), (char*)As + 4096 + tid * 16);
    gld_lds16(Bb + (size_t)rowa        * K + (k0 + kc), (char*)Bs + tid * 16);
    gld_lds16(Bb + (size_t)(rowa + 64) * K + (k0 + kc), (char*)Bs + 4096 + tid * 16);
    __syncthreads();
    short8 af[4], bfr[4];
    #pragma unroll
    for (int i = 0; i < 4; i++)
      af[i] = *reinterpret_cast<const short8*>(As + (wm + i * 16 + l16) * 32 + quad * 8);
    #pragma unroll
    for (int j = 0; j < 4; j++)
      bfr[j] = *reinterpret_cast<const short8*>(Bs + (wn + j * 16 + l16) * 32 + quad * 8);
    #pragma unroll
    for (int i = 0; i < 4; i++)
      #pragma unroll
      for (int j = 0; j < 4; j++)
        acc[i][j] = __builtin_amdgcn_mfma_f32_16x16x32_bf16(af[i], bfr[j], acc[i][j], 0, 0, 0);
  }

  #pragma unroll
  for (int i = 0; i < 4; i++)
    #pragma unroll
    for (int j = 0; j < 4; j++) {
      const int row0 = bm + wm + i * 16 + quad * 4;
      const int col  = bn + wn + j * 16 + l16;
      #pragma unroll
      for (int r = 0; r < 4; r++)
        C[(size_t)(row0 + r) * N + col] = acc[i][j][r];
    }
}

// ---------------------------------------------------------------- segment bounds
__global__ __launch_bounds__(256)
void seg_kernel(const int* __restrict__ sid, int* __restrict__ segstart,
                int* __restrict__ segend) {
  const int i = blockIdx.x * 256 + threadIdx.x;   // 0..8191
  const int b = i >> 11, l = i & 2047;
  const int* row = sid + (size_t)b * LSEQ;
  const int v = row[l];
  int lo = 0, hi = l;
  while (lo < hi) { int mid = (lo + hi) >> 1; if (row[mid] < v) lo = mid + 1; else hi = mid; }
  segstart[i] = lo;
  lo = l + 1; hi = LSEQ;
  while (lo < hi) { int mid = (lo + hi) >> 1; if (row[mid] <= v) lo = mid + 1; else hi = mid; }
  segend[i] = lo;
}

// ---------------------------------------------------------------- QK-LN + RoPE + scatter (bf16 out)
// qkv: fp32 [NTOK][3072]; outputs bf16 [B][H][L][DH]
__global__ __launch_bounds__(256)
void rope_kernel(const float* __restrict__ qkv, const float* __restrict__ qw,
                 const float* __restrict__ kw, unsigned short* __restrict__ qT,
                 unsigned short* __restrict__ kT, unsigned short* __restrict__ vN) {
  const int t = blockIdx.x, tid = threadIdx.x;
  const int b = t >> 11, l = t & 2047;
  const float* row = qkv + (size_t)t * K3;
  const float4 q4 = reinterpret_cast<const float4*>(row)[tid];
  const float4 k4 = reinterpret_cast<const float4*>(row + 1024)[tid];
  const float4 v4 = reinterpret_cast<const float4*>(row + 2048)[tid];
  float qs  = q4.x + q4.y + q4.z + q4.w;
  float qss = q4.x*q4.x + q4.y*q4.y + q4.z*q4.z + q4.w*q4.w;
  float ks  = k4.x + k4.y + k4.z + k4.w;
  float kss = k4.x*k4.x + k4.y*k4.y + k4.z*k4.z + k4.w*k4.w;
  #pragma unroll
  for (int off = 32; off > 0; off >>= 1) {
    qs  += __shfl_down(qs, off);  qss += __shfl_down(qss, off);
    ks  += __shfl_down(ks, off);  kss += __shfl_down(kss, off);
  }
  __shared__ float red[16];
  const int w = tid >> 6;
  if ((tid & 63) == 0) {
    red[w*4] = qs; red[w*4+1] = qss; red[w*4+2] = ks; red[w*4+3] = kss;
  }
  __syncthreads();
  qs  = red[0] + red[4] + red[8]  + red[12];
  qss = red[1] + red[5] + red[9]  + red[13];
  ks  = red[2] + red[6] + red[10] + red[14];
  kss = red[3] + red[7] + red[11] + red[15];
  const float qmu = qs * (1.f/1024), qvar = qss * (1.f/1024) - qmu*qmu;
  const float qrs = rsqrtf(qvar + 1e-5f);
  const float kmu = ks * (1.f/1024), kvar = kss * (1.f/1024) - kmu*kmu;
  const float krs = rsqrtf(kvar + 1e-5f);

  __shared__ float qn[1024];
  __shared__ float kn[1024];
  const float4 qwv = reinterpret_cast<const float4*>(qw)[tid];
  const float4 kwv = reinterpret_cast<const float4*>(kw)[tid];
  const int d = tid * 4;
  qn[d+0] = (q4.x - qmu) * qrs * qwv.x;
  qn[d+1] = (q4.y - qmu) * qrs * qwv.y;
  qn[d+2] = (q4.z - qmu) * qrs * qwv.z;
  qn[d+3] = (q4.w - qmu) * qrs * qwv.w;
  kn[d+0] = (k4.x - kmu) * krs * kwv.x;
  kn[d+1] = (k4.y - kmu) * krs * kwv.y;
  kn[d+2] = (k4.z - kmu) * krs * kwv.z;
  kn[d+3] = (k4.w - kmu) * krs * kwv.w;
  __syncthreads();

  const int hh = d >> 6, dh = d & 63;
  float oq[4], ok[4];
  #pragma unroll
  for (int i = 0; i < 4; i++) {
    const int dd = dh + i;
    const int j = dd & 31;
    const float th = (float)l * __expf(-(float)j * 0.28782313662425575f); // ln(1e4)/32
    const float cs = cosf(th), sn = sinf(th);
    const float qp = (dd < 32) ? -qn[d + i + 32] : qn[d + i - 32];
    const float kp = (dd < 32) ? -kn[d + i + 32] : kn[d + i - 32];
    oq[i] = qn[d + i] * cs + qp * sn;
    ok[i] = kn[d + i] * cs + kp * sn;
  }
  const size_t ob = ((size_t)(b * NH + hh) * LSEQ + l) * DH + dh;
  ushort4 pq, pk, pv;
  pq.x = f2bf_bits(oq[0]); pq.y = f2bf_bits(oq[1]); pq.z = f2bf_bits(oq[2]); pq.w = f2bf_bits(oq[3]);
  pk.x = f2bf_bits(ok[0]); pk.y = f2bf_bits(ok[1]); pk.z = f2bf_bits(ok[2]); pk.w = f2bf_bits(ok[3]);
  pv.x = f2bf_bits(v4.x);  pv.y = f2bf_bits(v4.y);  pv.z = f2bf_bits(v4.z);  pv.w = f2bf_bits(v4.w);
  *reinterpret_cast<ushort4*>(qT + ob) = pq;
  *reinterpret_cast<ushort4*>(kT + ob) = pk;
  *reinterpret_cast<ushort4*>(vN + ob) = pv;
}

// ---------------------------------------------------------------- V transpose per (b,h)
// vN: bf16 [BH][L][DH] -> vT: bf16 [BH][DH][L]
__global__ __launch_bounds__(256)
void vtrans(const unsigned short* __restrict__ vN, unsigned short* __restrict__ vT) {
  __shared__ __align__(16) unsigned short T[64 * 72];
  const int bh = blockIdx.y;
  const int l0 = blockIdx.x * 64;
  const int tid = threadIdx.x;
  #pragma unroll
  for (int it = 0; it < 2; it++) {
    const int cid = tid + it * 256;
    const int r = cid >> 3, c = (cid & 7) * 8;
    *reinterpret_cast<short8*>(T + r * 72 + c) =
        *reinterpret_cast<const short8*>(vN + ((size_t)bh * LSEQ + l0 + r) * DH + c);
  }
  __syncthreads();
  #pragma unroll
  for (int it = 0; it < 2; it++) {
    const int cid = tid + it * 256;
    const int dh = cid >> 3, c = (cid & 7) * 8;
    short8 o;
    #pragma unroll
    for (int e = 0; e < 8; e++) o[e] = (short)T[(c + e) * 72 + dh];
    *reinterpret_cast<short8*>(vT + ((size_t)bh * DH + dh) * LSEQ + l0 + c) = o;
  }
}

// ---------------------------------------------------------------- MFMA flash attention
// qT,kT: bf16 [BH][L][DH]; vT: bf16 [BH][DH][L]; ctx: bf16 [B][L][H*DH]
__global__ __launch_bounds__(256, 4)
void attn_mfma(const unsigned short* __restrict__ qT, const unsigned short* __restrict__ kT,
               const unsigned short* __restrict__ vT, const int* __restrict__ segs,
               const int* __restrict__ sege, unsigned short* __restrict__ ctx) {
  const int tid  = threadIdx.x;
  const int lane = tid & 63, w = tid >> 6;
  const int quad = lane >> 4, l16 = lane & 15;
  const int qt = blockIdx.x, h = blockIdx.y, b = blockIdx.z;
  const int qbase = qt * 64;
  const size_t bh = (size_t)(b * NH + h);
  const unsigned short* Qg = qT + (bh * LSEQ + qbase) * DH;
  const unsigned short* Kg = kT + bh * LSEQ * DH;
  const unsigned short* Vg = vT + bh * DH * LSEQ;

  __shared__ __align__(16) unsigned short Qs[64 * 72];
  __shared__ __align__(16) unsigned short Ks[64 * 72];
  __shared__ __align__(16) unsigned short Vs[64 * 72];
  __shared__ __align__(16) unsigned short Ps[64 * 72];
  __shared__ int segs_l[64], sege_l[64];

  #pragma unroll
  for (int it = 0; it < 2; it++) {
    const int cid = tid + it * 256;
    const int r = cid >> 3, c = (cid & 7) * 8;
    *reinterpret_cast<short8*>(Qs + r * 72 + c) =
        *reinterpret_cast<const short8*>(Qg + (size_t)r * DH + c);
  }
  if (tid < 64) {
    segs_l[tid] = segs[b * LSEQ + qbase + tid];
    sege_l[tid] = sege[b * LSEQ + qbase + tid];
  }
  __syncthreads();

  const int kmin = segs_l[0] & ~63;
  const int kmax = sege_l[63];
  const int qr = w * 16 + quad * 4;
  int st[4], en[4];
  #pragma unroll
  for (int r = 0; r < 4; r++) { st[r] = segs_l[qr + r]; en[r] = sege_l[qr + r]; }

  const short8 aq0 = *reinterpret_cast<const short8*>(Qs + (w * 16 + l16) * 72 + quad * 8);
  const short8 aq1 = *reinterpret_cast<const short8*>(Qs + (w * 16 + l16) * 72 + 32 + quad * 8);

  floatx4 acc[4];
  #pragma unroll
  for (int dt = 0; dt < 4; dt++) { floatx4 z = {0.f,0.f,0.f,0.f}; acc[dt] = z; }
  float m[4]    = {-1e30f, -1e30f, -1e30f, -1e30f};
  float lsum[4] = {0.f, 0.f, 0.f, 0.f};

  for (int kk = kmin; kk < kmax; kk += 64) {
    __syncthreads();
    #pragma unroll
    for (int it = 0; it < 2; it++) {
      const int cid = tid + it * 256;
      const int r = cid >> 3, c = (cid & 7) * 8;
      *reinterpret_cast<short8*>(Ks + r * 72 + c) =
          *reinterpret_cast<const short8*>(Kg + (size_t)(kk + r) * DH + c);
      *reinterpret_cast<short8*>(Vs + r * 72 + c) =
          *reinterpret_cast<const short8*>(Vg + (size_t)r * LSEQ + kk + c);
    }
    __syncthreads();

    // QK^T: 16q x 64k per wave
    floatx4 sc[4];
    #pragma unroll
    for (int j = 0; j < 4; j++) {
      const short8 bk0 = *reinterpret_cast<const short8*>(Ks + (j * 16 + l16) * 72 + quad * 8);
      const short8 bk1 = *reinterpret_cast<const short8*>(Ks + (j * 16 + l16) * 72 + 32 + quad * 8);
      floatx4 z = {0.f,0.f,0.f,0.f};
      sc[j] = __builtin_amdgcn_mfma_f32_16x16x32_bf16(aq0, bk0, z, 0, 0, 0);
      sc[j] = __builtin_amdgcn_mfma_f32_16x16x32_bf16(aq1, bk1, sc[j], 0, 0, 0);
    }

    // online softmax per row (row = qr + r), lanes l16 hold k = kk + j*16 + l16
    float alpha[4];
    #pragma unroll
    for (int r = 0; r < 4; r++) {
      float sv[4];
      float vm = -1e30f;
      #pragma unroll
      for (int j = 0; j < 4; j++) {
        float s = sc[j][r] * 0.125f;
        const int k = kk + j * 16 + l16;
        const bool ok = (k >= st[r]) && (k < en[r]);
        s = ok ? s : -1e30f;
        sv[j] = s;
        vm = fmaxf(vm, s);
      }
      vm = fmaxf(vm, __shfl_xor(vm, 1));
      vm = fmaxf(vm, __shfl_xor(vm, 2));
      vm = fmaxf(vm, __shfl_xor(vm, 4));
      vm = fmaxf(vm, __shfl_xor(vm, 8));
      const float mn = fmaxf(m[r], vm);
      const float a  = __expf(m[r] - mn);   // m==mn==-1e30 -> exp(0)=1, lsum stays 0
      float rs = 0.f;
      #pragma unroll
      for (int j = 0; j < 4; j++) {
        const float pe = (sv[j] > -1e29f) ? __expf(sv[j] - mn) : 0.f;
        Ps[(qr + r) * 72 + j * 16 + l16] = f2bf_bits(pe);
        rs += pe;
      }
      rs += __shfl_xor(rs, 1);
      rs += __shfl_xor(rs, 2);
      rs += __shfl_xor(rs, 4);
      rs += __shfl_xor(rs, 8);
      lsum[r] = lsum[r] * a + rs;
      m[r] = mn;
      alpha[r] = a;
    }

    // PV: acc = alpha*acc + P @ V  (intra-wave LDS round-trip; DS ops in-order per wave)
    const short8 ap0 = *reinterpret_cast<const short8*>(Ps + (w * 16 + l16) * 72 + quad * 8);
    const short8 ap1 = *reinterpret_cast<const short8*>(Ps + (w * 16 + l16) * 72 + 32 + quad * 8);
    #pragma unroll
    for (int dt = 0; dt < 4; dt++) {
      #pragma unroll
      for (int r = 0; r < 4; r++) acc[dt][r] *= alpha[r];
      const short8 bv0 = *reinterpret_cast<const short8*>(Vs + (dt * 16 + l16) * 72 + quad * 8);
      const short8 bv1 = *reinterpret_cast<const short8*>(Vs + (dt * 16 + l16) * 72 + 32 + quad * 8);
      acc[dt] = __builtin_amdgcn_mfma_f32_16x16x32_bf16(ap0, bv0, acc[dt], 0, 0, 0);
      acc[dt] = __builtin_amdgcn_mfma_f32_16x16x32_bf16(ap1, bv1, acc[dt], 0, 0, 0);
    }
  }

  // epilogue: normalize, repack via own Ps band, vector store
  float inv[4];
  #pragma unroll
  for (int r = 0; r < 4; r++) inv[r] = (lsum[r] > 0.f) ? 1.f / lsum[r] : 0.f;
  #pragma unroll
  for (int dt = 0; dt < 4; dt++)
    #pragma unroll
    for (int r = 0; r < 4; r++)
      Ps[(qr + r) * 72 + dt * 16 + l16] = f2bf_bits(acc[dt][r] * inv[r]);
  #pragma unroll
  for (int e = 0; e < 2; e++) {
    const short8 o = *reinterpret_cast<const short8*>(Ps + (w * 16 + l16) * 72 + quad * 16 + e * 8);
    *reinterpret_cast<short8*>(ctx + ((size_t)(b * LSEQ + qbase + w * 16 + l16)) * D_MODEL
                               + h * DH + quad * 16 + e * 8) = o;
  }
}

// ---------------------------------------------------------------- launch
extern "C" void kernel_launch(void* const* d_in, const int* in_sizes, int n_in,
                              void* d_out, int out_size, void* d_ws, size_t ws_size,
                              hipStream_t stream) {
  const float* x      = (const float*)d_in[0];
  const int*   sid    = (const int*)d_in[1];
  const float* ln_w   = (const float*)d_in[2];
  const float* ln_b   = (const float*)d_in[3];
  const float* w_qkv  = (const float*)d_in[4];
  const float* q_ln_w = (const float*)d_in[5];
  const float* k_ln_w = (const float*)d_in[6];
  const float* w_out  = (const float*)d_in[7];
  float* out = (float*)d_out;
  char* ws = (char*)d_ws;

  constexpr size_t OFF_WQKVT = 0;                        // 6,291,456
  constexpr size_t OFF_WOUTT = 6291456;                  // 2,097,152
  constexpr size_t OFF_H     = 8388608;                  // 16,777,216
  constexpr size_t OFF_QKV   = 25165824;                 // 100,663,296
  constexpr size_t OFF_QT    = 125829120;                // 16,777,216 (bf16)
  constexpr size_t OFF_KT    = 142606336;                // 16,777,216
  constexpr size_t OFF_VN    = 159383552;                // 16,777,216
  constexpr size_t OFF_VT    = 176160768;                // 16,777,216
  constexpr size_t OFF_CTX   = 192937984;                // 16,777,216
  constexpr size_t OFF_SEGS  = 209715200;                // 32,768
  constexpr size_t OFF_SEGE  = 209747968;                // 32,768

  __hip_bfloat16* wqkvT = (__hip_bfloat16*)(ws + OFF_WQKVT);
  __hip_bfloat16* woutT = (__hip_bfloat16*)(ws + OFF_WOUTT);
  __hip_bfloat16* hbuf  = (__hip_bfloat16*)(ws + OFF_H);
  float*          qkv   = (float*)(ws + OFF_QKV);
  unsigned short* qTb   = (unsigned short*)(ws + OFF_QT);
  unsigned short* kTb   = (unsigned short*)(ws + OFF_KT);
  unsigned short* vNb   = (unsigned short*)(ws + OFF_VN);
  unsigned short* vTb   = (unsigned short*)(ws + OFF_VT);
  unsigned short* ctx   = (unsigned short*)(ws + OFF_CTX);
  int*            segst = (int*)(ws + OFF_SEGS);
  int*            segen = (int*)(ws + OFF_SEGE);

  transpose_cast<<<dim3(96, 32), dim3(32, 8), 0, stream>>>(w_qkv, wqkvT, 1024, 3072);
  transpose_cast<<<dim3(32, 32), dim3(32, 8), 0, stream>>>(w_out, woutT, 1024, 1024);
  ln_kernel<<<NTOK, 256, 0, stream>>>(x, ln_w, ln_b, hbuf);
  gemm_bt<<<dim3(K3 / 128, NTOK / 128), 256, 0, stream>>>(hbuf, wqkvT, qkv, NTOK, K3, 1024);
  seg_kernel<<<NTOK / 256, 256, 0, stream>>>(sid, segst, segen);
  rope_kernel<<<NTOK, 256, 0, stream>>>(qkv, q_ln_w, k_ln_w, qTb, kTb, vNb);
  vtrans<<<dim3(LSEQ / 64, BATCH * NH), 256, 0, stream>>>(vNb, vTb);
  attn_mfma<<<dim3(LSEQ / 64, NH, BATCH), 256, 0, stream>>>(qTb, kTb, vTb, segst, segen, ctx);
  gemm_bt<<<dim3(D_MODEL / 128, NTOK / 128), 256, 0, stream>>>(
      (const __hip_bfloat16*)ctx, woutT, out, NTOK, D_MODEL, 1024);
}